// Round 2
// baseline (704.316 us; speedup 1.0000x reference)
//
#include <hip/hip_runtime.h>

typedef unsigned short u16;
typedef __attribute__((ext_vector_type(8))) short bf16x8;
typedef __attribute__((ext_vector_type(4))) float f32x4;
typedef __attribute__((ext_vector_type(4))) unsigned int u32x4;

#define GAS __attribute__((address_space(1)))
#define LAS __attribute__((address_space(3)))

__device__ __forceinline__ void gload16(const void* g, void* l) {
  __builtin_amdgcn_global_load_lds((GAS void*)g, (LAS void*)l, 16, 0, 0);
}
__device__ __forceinline__ u16 f2b(float x) {
  union { float f; unsigned u; } c; c.f = x;
  unsigned r = c.u + 0x7fffu + ((c.u >> 16) & 1u);
  return (u16)(r >> 16);
}
__device__ __forceinline__ float b2f(u16 h) {
  union { unsigned u; float f; } c; c.u = ((unsigned)h) << 16;
  return c.f;
}

// ---------------- fp32 -> bf16 conversion (8 elems/thread) ----------------
__global__ __launch_bounds__(256) void cvt_bf16(const float* __restrict__ src,
                                                u16* __restrict__ dst, int n8) {
  int i = blockIdx.x * 256 + threadIdx.x;
  if (i >= n8) return;
  const float4* s4 = (const float4*)src;
  float4 a = s4[(size_t)i * 2], b = s4[(size_t)i * 2 + 1];
  u32x4 v;
  v[0] = (unsigned)f2b(a.x) | ((unsigned)f2b(a.y) << 16);
  v[1] = (unsigned)f2b(a.z) | ((unsigned)f2b(a.w) << 16);
  v[2] = (unsigned)f2b(b.x) | ((unsigned)f2b(b.y) << 16);
  v[3] = (unsigned)f2b(b.z) | ((unsigned)f2b(b.w) << 16);
  *(u32x4*)(dst + (size_t)i * 8) = v;
}

// ---------------- GEMM: C[m,n] = sum_k A[m,k]*B[n,k]  (B given row=n, K-major)
// 128x128 tile, BK=32, 4 waves (2x2), each wave 64x64 via 4x4 mfma frags.
// LDS 16B-slot involution swizzle: phys(row,kc) = row*4 + (kc ^ (row&3)).
template <int MODE>
__global__ __launch_bounds__(256) void gemm_bt(
    const u16* __restrict__ A, const u16* __restrict__ B,
    u16* __restrict__ Dq, u16* __restrict__ Dk, u16* __restrict__ Dv,
    float* __restrict__ Dout, int M, int N, int K) {
  __shared__ __attribute__((aligned(16))) u16 As[128 * 32];
  __shared__ __attribute__((aligned(16))) u16 Bs[128 * 32];
  const int tid = threadIdx.x;
  const int lane = tid & 63;
  const int w = tid >> 6;
  const int wr = w >> 1, wc = w & 1;
  const int r = lane & 15, g = lane >> 4;
  const int m0 = blockIdx.y * 128, n0 = blockIdx.x * 128;
  (void)M; (void)N;

  f32x4 acc[4][4];
#pragma unroll
  for (int i = 0; i < 4; ++i)
#pragma unroll
    for (int j = 0; j < 4; ++j) acc[i][j] = (f32x4){0.f, 0.f, 0.f, 0.f};

  for (int k0 = 0; k0 < K; k0 += 32) {
#pragma unroll
    for (int c = 0; c < 2; ++c) {
      int t = c * 256 + tid;          // 16B slot index in [0,512)
      int row = t >> 2;               // row unchanged by swizzle (XOR hits bits 0-1)
      int kc = (t & 3) ^ ((t >> 2) & 3);
      gload16(A + (size_t)(m0 + row) * K + k0 + kc * 8, (char*)As + c * 4096 + w * 1024);
      gload16(B + (size_t)(n0 + row) * K + k0 + kc * 8, (char*)Bs + c * 4096 + w * 1024);
    }
    __syncthreads();  // drains vmcnt; LDS tiles ready

    bf16x8 af[4], bfr[4];
#pragma unroll
    for (int mi = 0; mi < 4; ++mi) {
      int ro = wr * 64 + mi * 16 + r;
      int slot = (ro * 4 + g) ^ (ro & 3);
      af[mi] = *(const bf16x8*)((const char*)As + slot * 16);
    }
#pragma unroll
    for (int ni = 0; ni < 4; ++ni) {
      int ro = wc * 64 + ni * 16 + r;
      int slot = (ro * 4 + g) ^ (ro & 3);
      bfr[ni] = *(const bf16x8*)((const char*)Bs + slot * 16);
    }
#pragma unroll
    for (int mi = 0; mi < 4; ++mi)
#pragma unroll
      for (int ni = 0; ni < 4; ++ni)
        acc[mi][ni] = __builtin_amdgcn_mfma_f32_16x16x32_bf16(af[mi], bfr[ni],
                                                              acc[mi][ni], 0, 0, 0);
    __syncthreads();  // all reads done before restage
  }

  // Epilogue. D layout: col = lane&15 (=r), row = (lane>>4)*4 + j (=g*4+j).
#pragma unroll
  for (int mi = 0; mi < 4; ++mi)
#pragma unroll
    for (int ni = 0; ni < 4; ++ni)
#pragma unroll
      for (int j = 0; j < 4; ++j) {
        int m = m0 + wr * 64 + mi * 16 + g * 4 + j;
        int n = n0 + wc * 64 + ni * 16 + r;
        float v = acc[mi][ni][j];
        if (MODE == 0) {
          u16 hv = f2b(v);
          int b = m >> 11, s = m & 2047;
          if (n < 4096) {
            Dq[(((size_t)b * 32 + (n >> 7)) * 2048 + s) * 128 + (n & 127)] = hv;
          } else if (n < 5120) {
            int nn = n - 4096;
            Dk[(((size_t)b * 8 + (nn >> 7)) * 2048 + s) * 128 + (nn & 127)] = hv;
          } else {
            int nn = n - 5120;
            Dv[(((size_t)b * 8 + (nn >> 7)) * 2048 + s) * 128 + (nn & 127)] = hv;
          }
        } else {
          Dout[(size_t)m * 2048 + n] = v;
        }
      }
}

// ---------------- fused per-head RMSNorm + RoPE (in place, bf16) ----------------
// one wave per 128-elem row; lane l holds d=l and d=l+64 (rotate_half pair).
__global__ __launch_bounds__(256) void rms_rope(u16* __restrict__ X,
                                                const float* __restrict__ cosT,
                                                const float* __restrict__ sinT,
                                                const float* __restrict__ nw,
                                                int nrows, float oscale) {
  int idx = blockIdx.x * 256 + threadIdx.x;
  int row = idx >> 6;
  int lane = idx & 63;
  if (row >= nrows) return;
  int s = row & 2047;  // S = 2048
  u16* rp = X + (size_t)row * 128;
  float x0 = b2f(rp[lane]);
  float x1 = b2f(rp[lane + 64]);
  float ss = x0 * x0 + x1 * x1;
#pragma unroll
  for (int m = 32; m >= 1; m >>= 1) ss += __shfl_xor(ss, m);
  float inv = rsqrtf(ss * (1.0f / 128.0f) + 1e-6f);
  x0 *= inv * nw[lane];
  x1 *= inv * nw[lane + 64];
  float c0 = cosT[s * 128 + lane], s0 = sinT[s * 128 + lane];
  float c1 = cosT[s * 128 + lane + 64], s1 = sinT[s * 128 + lane + 64];
  rp[lane] = f2b((x0 * c0 - x1 * s0) * oscale);
  rp[lane + 64] = f2b((x1 * c1 + x0 * s1) * oscale);
}

// ---------------- causal GQA flash attention ----------------
// block = (qt, h, b): 4 waves x 16 q-rows = 64 q rows; KV tiles of 32.
// K staged [32][128] via global_load_lds with involution swizzle:
//   phys(krow, kc16) = krow*16 + (kc16 ^ (krow&7))      (16B granules)
// V staged TRANSPOSED via registers: Vt[d][kv] (128x32), granule swizzle:
//   phys_gran(d, kv8) = kv8 ^ ((d>>1)&3)                (16B granules, 4/row)
__global__ __launch_bounds__(256) void attn_fwd(const u16* __restrict__ Q,
                                                const u16* __restrict__ Kg,
                                                const u16* __restrict__ Vg,
                                                u16* __restrict__ AO) {
  __shared__ __attribute__((aligned(16))) u16 Ks[32 * 128];
  __shared__ __attribute__((aligned(16))) u16 Vt[128 * 32];
  __shared__ __attribute__((aligned(16))) u16 Plds[4][16 * 32];
  const int tid = threadIdx.x;
  const int lane = tid & 63;
  const int w = tid >> 6;
  const int r = lane & 15, g = lane >> 4;
  const int qt = blockIdx.x, h = blockIdx.y, b = blockIdx.z;
  const int hkv = h >> 2;

  const u16* Qp = Q + (((size_t)b * 32 + h) * 2048 + qt * 64 + w * 16) * 128;
  const u16* Kp = Kg + (((size_t)b * 8 + hkv) * 2048) * 128;
  const u16* Vp = Vg + (((size_t)b * 8 + hkv) * 2048) * 128;

  // V staging assignment: thread handles d0 = (tid&63)*2 (+1), kv0 = (tid>>6)*8
  const int vd0 = (tid & 63) * 2;
  const int vgq = tid >> 6;
  const int vph = vgq ^ ((vd0 >> 1) & 3);  // phys granule for both rows d0, d0+1

  // Q fragments: A-operand row = r, k(d) = kk*32 + g*8 + e
  bf16x8 qf[4];
#pragma unroll
  for (int kk = 0; kk < 4; ++kk)
    qf[kk] = *(const bf16x8*)(Qp + r * 128 + kk * 32 + g * 8);

  f32x4 off[8];
#pragma unroll
  for (int i = 0; i < 8; ++i) off[i] = (f32x4){0.f, 0.f, 0.f, 0.f};
  float mrun[4], lrun[4];
#pragma unroll
  for (int j = 0; j < 4; ++j) { mrun[j] = -1e30f; lrun[j] = 0.f; }

  const int q_base = qt * 64 + w * 16 + g * 4;
  const int nt = (qt + 1) * 2;

  for (int kt = 0; kt < nt; ++kt) {
    // ---- stage K via global_load_lds (swizzled granules)
#pragma unroll
    for (int c = 0; c < 2; ++c) {
      int t = c * 256 + tid;  // 16B slot in [0,512)
      int krow = t >> 4;
      int kcc = (t & 15) ^ (krow & 7);
      gload16(Kp + (size_t)(kt * 32 + krow) * 128 + kcc * 8, (char*)Ks + c * 4096 + w * 1024);
    }
    // ---- stage V transposed via registers (coalesced u32 global loads)
    {
      unsigned vv[8];
#pragma unroll
      for (int i = 0; i < 8; ++i)
        vv[i] = *(const unsigned*)(Vp + (size_t)(kt * 32 + vgq * 8 + i) * 128 + vd0);
      u32x4 lo, hi;
#pragma unroll
      for (int i = 0; i < 4; ++i) {
        lo[i] = (vv[2 * i] & 0xffffu) | (vv[2 * i + 1] << 16);
        hi[i] = (vv[2 * i] >> 16) | (vv[2 * i + 1] & 0xffff0000u);
      }
      *(u32x4*)((char*)Vt + (size_t)vd0 * 64 + vph * 16) = lo;
      *(u32x4*)((char*)Vt + (size_t)(vd0 + 1) * 64 + vph * 16) = hi;
    }
    __syncthreads();

    // ---- S = Q K^T  (D[q_local][kv_local], col=r is kv, row=g*4+j is q)
    f32x4 sc[2];
#pragma unroll
    for (int ni = 0; ni < 2; ++ni) {
      f32x4 a = (f32x4){0.f, 0.f, 0.f, 0.f};
      int ro = ni * 16 + r;
#pragma unroll
      for (int kk = 0; kk < 4; ++kk) {
        int slot = (ro * 16 + kk * 4 + g) ^ (ro & 7);
        bf16x8 kf = *(const bf16x8*)((const char*)Ks + slot * 16);
        a = __builtin_amdgcn_mfma_f32_16x16x32_bf16(qf[kk], kf, a, 0, 0, 0);
      }
      sc[ni] = a;
    }

    // ---- mask + online softmax (1/sqrt(128) pre-folded into Q)
    float pm[4] = {-3e30f, -3e30f, -3e30f, -3e30f};
#pragma unroll
    for (int ni = 0; ni < 2; ++ni) {
      int kvg = kt * 32 + ni * 16 + r;
#pragma unroll
      for (int j = 0; j < 4; ++j) {
        float sv = sc[ni][j];
        sv = (kvg > q_base + j) ? -1e30f : sv;
        sc[ni][j] = sv;
        pm[j] = fmaxf(pm[j], sv);
      }
    }
#pragma unroll
    for (int j = 0; j < 4; ++j) {
      pm[j] = fmaxf(pm[j], __shfl_xor(pm[j], 1));
      pm[j] = fmaxf(pm[j], __shfl_xor(pm[j], 2));
      pm[j] = fmaxf(pm[j], __shfl_xor(pm[j], 4));
      pm[j] = fmaxf(pm[j], __shfl_xor(pm[j], 8));
    }
    float scl[4], psum[4];
#pragma unroll
    for (int j = 0; j < 4; ++j) {
      float mn = fmaxf(mrun[j], pm[j]);
      scl[j] = __expf(mrun[j] - mn);
      mrun[j] = mn;
      psum[j] = 0.f;
    }
    u16 pb[2][4];
#pragma unroll
    for (int ni = 0; ni < 2; ++ni)
#pragma unroll
      for (int j = 0; j < 4; ++j) {
        float p = __expf(sc[ni][j] - mrun[j]);
        psum[j] += p;
        pb[ni][j] = f2b(p);
      }
#pragma unroll
    for (int j = 0; j < 4; ++j) {
      psum[j] += __shfl_xor(psum[j], 1);
      psum[j] += __shfl_xor(psum[j], 2);
      psum[j] += __shfl_xor(psum[j], 4);
      psum[j] += __shfl_xor(psum[j], 8);
      lrun[j] = lrun[j] * scl[j] + psum[j];
    }
#pragma unroll
    for (int i = 0; i < 8; ++i)
#pragma unroll
      for (int j = 0; j < 4; ++j) off[i][j] *= scl[j];

    // ---- P through per-wave LDS to get A-operand layout (row=r, k=g*8+e)
#pragma unroll
    for (int ni = 0; ni < 2; ++ni)
#pragma unroll
      for (int j = 0; j < 4; ++j)
        Plds[w][(g * 4 + j) * 32 + ni * 16 + r] = pb[ni][j];

    bf16x8 pa = *(const bf16x8*)(&Plds[w][0] + r * 32 + g * 8);

    // ---- V fragments: B-operand col(d)=dd*16+r, k(kv)=g*8+e
#pragma unroll
    for (int dd = 0; dd < 8; ++dd) {
      int d = dd * 16 + r;
      int ph = g ^ ((r >> 1) & 3);
      bf16x8 vf = *(const bf16x8*)((const char*)Vt + (size_t)d * 64 + ph * 16);
      off[dd] = __builtin_amdgcn_mfma_f32_16x16x32_bf16(pa, vf, off[dd], 0, 0, 0);
    }
    __syncthreads();  // all waves done with Ks/Vt before restage
  }

  const size_t orow_base = (size_t)b * 2048 + qt * 64 + w * 16 + g * 4;
#pragma unroll
  for (int dd = 0; dd < 8; ++dd)
#pragma unroll
    for (int j = 0; j < 4; ++j) {
      float o = off[dd][j] / lrun[j];
      AO[(orow_base + j) * 4096 + h * 128 + dd * 16 + r] = f2b(o);
    }
}

// ---------------- launch ----------------
extern "C" void kernel_launch(void* const* d_in, const int* in_sizes, int n_in,
                              void* d_out, int out_size, void* d_ws, size_t ws_size,
                              hipStream_t stream) {
  (void)in_sizes; (void)n_in; (void)out_size; (void)ws_size;
  const float* hs = (const float*)d_in[0];
  const float* cosT = (const float*)d_in[1];
  const float* sinT = (const float*)d_in[2];
  const float* wq = (const float*)d_in[3];
  const float* wk = (const float*)d_in[4];
  const float* wv = (const float*)d_in[5];
  const float* wo = (const float*)d_in[6];
  const float* qnw = (const float*)d_in[7];
  const float* knw = (const float*)d_in[8];
  float* out = (float*)d_out;

  char* ws = (char*)d_ws;
  u16* hsb  = (u16*)(ws);                   // [4096,2048]      16 MB
  u16* wqkv = (u16*)(ws + 16777216);        // [6144,2048]      24 MB
  u16* wob  = (u16*)(ws + 41943040);        // [2048,4096]      16 MB
  u16* Qb   = (u16*)(ws + 58720256);        // [2,32,2048,128]  32 MB
  u16* Kb   = (u16*)(ws + 92274688);        // [2,8,2048,128]    8 MB
  u16* Vb   = (u16*)(ws + 100663296);       // [2,8,2048,128]    8 MB
  u16* AO   = (u16*)(ws + 109051904);       // [4096,4096]      32 MB

  // 1) fp32 -> bf16
  cvt_bf16<<<4096, 256, 0, stream>>>(hs, hsb, 1048576);
  cvt_bf16<<<4096, 256, 0, stream>>>(wq, wqkv, 1048576);
  cvt_bf16<<<1024, 256, 0, stream>>>(wk, wqkv + (size_t)4096 * 2048, 262144);
  cvt_bf16<<<1024, 256, 0, stream>>>(wv, wqkv + (size_t)5120 * 2048, 262144);
  cvt_bf16<<<4096, 256, 0, stream>>>(wo, wob, 1048576);

  // 2) fused QKV projection, scatter into [B,H,S,D]
  gemm_bt<0><<<dim3(48, 32), 256, 0, stream>>>(hsb, wqkv, Qb, Kb, Vb, nullptr,
                                               4096, 6144, 2048);

  // 3) per-head RMSNorm + RoPE (Q gets softmax scale folded in)
  rms_rope<<<32768, 256, 0, stream>>>(Qb, cosT, sinT, qnw, 131072, 0.08838834764831845f);
  rms_rope<<<8192, 256, 0, stream>>>(Kb, cosT, sinT, knw, 32768, 1.0f);

  // 4) causal GQA flash attention -> AO [B*S, 4096] bf16
  attn_fwd<<<dim3(32, 32, 2), 256, 0, stream>>>(Qb, Kb, Vb, AO);

  // 5) output projection -> fp32 d_out
  gemm_bt<1><<<dim3(16, 32), 256, 0, stream>>>(AO, wob, nullptr, nullptr, nullptr,
                                               out, 4096, 2048, 4096);
}

// Round 3
// 500.760 us; speedup vs baseline: 1.4065x; 1.4065x over previous
//
#include <hip/hip_runtime.h>

typedef unsigned short u16;
typedef __attribute__((ext_vector_type(8))) short bf16x8;
typedef __attribute__((ext_vector_type(4))) float f32x4;
typedef __attribute__((ext_vector_type(4))) unsigned int u32x4;

#define GAS __attribute__((address_space(1)))
#define LAS __attribute__((address_space(3)))

__device__ __forceinline__ void gload16(const void* g, void* l) {
  __builtin_amdgcn_global_load_lds((GAS void*)g, (LAS void*)l, 16, 0, 0);
}
__device__ __forceinline__ u16 f2b(float x) {
  union { float f; unsigned u; } c; c.f = x;
  unsigned r = c.u + 0x7fffu + ((c.u >> 16) & 1u);
  return (u16)(r >> 16);
}
__device__ __forceinline__ float b2f(u16 h) {
  union { unsigned u; float f; } c; c.u = ((unsigned)h) << 16;
  return c.f;
}

// ---------------- fp32 -> bf16 conversion (8 elems/thread) ----------------
__global__ __launch_bounds__(256) void cvt_bf16(const float* __restrict__ src,
                                                u16* __restrict__ dst, int n8) {
  int i = blockIdx.x * 256 + threadIdx.x;
  if (i >= n8) return;
  const float4* s4 = (const float4*)src;
  float4 a = s4[(size_t)i * 2], b = s4[(size_t)i * 2 + 1];
  u32x4 v;
  v[0] = (unsigned)f2b(a.x) | ((unsigned)f2b(a.y) << 16);
  v[1] = (unsigned)f2b(a.z) | ((unsigned)f2b(a.w) << 16);
  v[2] = (unsigned)f2b(b.x) | ((unsigned)f2b(b.y) << 16);
  v[3] = (unsigned)f2b(b.z) | ((unsigned)f2b(b.w) << 16);
  *(u32x4*)(dst + (size_t)i * 8) = v;
}

// ---------------- GEMM: C[m,n] = sum_k A[m,k]*B[n,k]  (B given row=n, K-major)
// 128x128 tile, BK=32, 4 waves (2x2), each wave 64x64 via 4x4 mfma frags.
// LDS 16B-slot involution swizzle: phys(row,kc) = row*4 + (kc ^ (row&3)).
template <int MODE>
__global__ __launch_bounds__(256) void gemm_bt(
    const u16* __restrict__ A, const u16* __restrict__ B,
    u16* __restrict__ Dq, u16* __restrict__ Dk, u16* __restrict__ Dv,
    float* __restrict__ Dout, int M, int N, int K) {
  __shared__ __attribute__((aligned(16))) u16 As[128 * 32];
  __shared__ __attribute__((aligned(16))) u16 Bs[128 * 32];
  const int tid = threadIdx.x;
  const int lane = tid & 63;
  const int w = tid >> 6;
  const int wr = w >> 1, wc = w & 1;
  const int r = lane & 15, g = lane >> 4;
  const int m0 = blockIdx.y * 128, n0 = blockIdx.x * 128;
  (void)M; (void)N;

  f32x4 acc[4][4];
#pragma unroll
  for (int i = 0; i < 4; ++i)
#pragma unroll
    for (int j = 0; j < 4; ++j) acc[i][j] = (f32x4){0.f, 0.f, 0.f, 0.f};

  for (int k0 = 0; k0 < K; k0 += 32) {
#pragma unroll
    for (int c = 0; c < 2; ++c) {
      int t = c * 256 + tid;          // 16B slot index in [0,512)
      int row = t >> 2;               // row unchanged by swizzle (XOR hits bits 0-1)
      int kc = (t & 3) ^ ((t >> 2) & 3);
      gload16(A + (size_t)(m0 + row) * K + k0 + kc * 8, (char*)As + c * 4096 + w * 1024);
      gload16(B + (size_t)(n0 + row) * K + k0 + kc * 8, (char*)Bs + c * 4096 + w * 1024);
    }
    __syncthreads();  // drains vmcnt; LDS tiles ready

    bf16x8 af[4], bfr[4];
#pragma unroll
    for (int mi = 0; mi < 4; ++mi) {
      int ro = wr * 64 + mi * 16 + r;
      int slot = (ro * 4 + g) ^ (ro & 3);
      af[mi] = *(const bf16x8*)((const char*)As + slot * 16);
    }
#pragma unroll
    for (int ni = 0; ni < 4; ++ni) {
      int ro = wc * 64 + ni * 16 + r;
      int slot = (ro * 4 + g) ^ (ro & 3);
      bfr[ni] = *(const bf16x8*)((const char*)Bs + slot * 16);
    }
#pragma unroll
    for (int mi = 0; mi < 4; ++mi)
#pragma unroll
      for (int ni = 0; ni < 4; ++ni)
        acc[mi][ni] = __builtin_amdgcn_mfma_f32_16x16x32_bf16(af[mi], bfr[ni],
                                                              acc[mi][ni], 0, 0, 0);
    __syncthreads();  // all reads done before restage
  }

  // Epilogue. D layout: col = lane&15 (=r), row = (lane>>4)*4 + j (=g*4+j).
#pragma unroll
  for (int mi = 0; mi < 4; ++mi)
#pragma unroll
    for (int ni = 0; ni < 4; ++ni)
#pragma unroll
      for (int j = 0; j < 4; ++j) {
        int m = m0 + wr * 64 + mi * 16 + g * 4 + j;
        int n = n0 + wc * 64 + ni * 16 + r;
        float v = acc[mi][ni][j];
        if (MODE == 0) {
          u16 hv = f2b(v);
          int b = m >> 11, s = m & 2047;
          if (n < 4096) {
            Dq[(((size_t)b * 32 + (n >> 7)) * 2048 + s) * 128 + (n & 127)] = hv;
          } else if (n < 5120) {
            int nn = n - 4096;
            Dk[(((size_t)b * 8 + (nn >> 7)) * 2048 + s) * 128 + (nn & 127)] = hv;
          } else {
            int nn = n - 5120;
            Dv[(((size_t)b * 8 + (nn >> 7)) * 2048 + s) * 128 + (nn & 127)] = hv;
          }
        } else {
          Dout[(size_t)m * 2048 + n] = v;
        }
      }
}

// ---------------- fused per-head RMSNorm + RoPE (in place, bf16) ----------------
__global__ __launch_bounds__(256) void rms_rope(u16* __restrict__ X,
                                                const float* __restrict__ cosT,
                                                const float* __restrict__ sinT,
                                                const float* __restrict__ nw,
                                                int nrows, float oscale) {
  int idx = blockIdx.x * 256 + threadIdx.x;
  int row = idx >> 6;
  int lane = idx & 63;
  if (row >= nrows) return;
  int s = row & 2047;  // S = 2048
  u16* rp = X + (size_t)row * 128;
  float x0 = b2f(rp[lane]);
  float x1 = b2f(rp[lane + 64]);
  float ss = x0 * x0 + x1 * x1;
#pragma unroll
  for (int m = 32; m >= 1; m >>= 1) ss += __shfl_xor(ss, m);
  float inv = rsqrtf(ss * (1.0f / 128.0f) + 1e-6f);
  x0 *= inv * nw[lane];
  x1 *= inv * nw[lane + 64];
  float c0 = cosT[s * 128 + lane], s0 = sinT[s * 128 + lane];
  float c1 = cosT[s * 128 + lane + 64], s1 = sinT[s * 128 + lane + 64];
  rp[lane] = f2b((x0 * c0 - x1 * s0) * oscale);
  rp[lane + 64] = f2b((x1 * c1 + x0 * s1) * oscale);
}

// ---------------- causal GQA flash attention (paired Q-tiles) ----------------
// block p handles Q-tiles {31-p, p} (uniform 33 KV-units). 4 waves x 16 q-rows.
// KVBLK = 64. K staged [64][128] via global_load_lds, granule swizzle
//   phys(krow,kc) = krow*16 + (kc ^ (krow&7)).
// V staged transposed Vt[128][64] via registers, granule swizzle
//   phys_gran(d,kvg) = kvg ^ ((d>>1)&7).
// P per-wave LDS [16][64], granule swizzle phys = gran ^ (qrow&7).
__global__ __launch_bounds__(256) void attn_fwd(const u16* __restrict__ Q,
                                                const u16* __restrict__ Kg,
                                                const u16* __restrict__ Vg,
                                                u16* __restrict__ AO) {
  __shared__ __attribute__((aligned(16))) u16 Ks[64 * 128];
  __shared__ __attribute__((aligned(16))) u16 Vt[128 * 64];
  __shared__ __attribute__((aligned(16))) u16 Plds[4][16 * 64];
  const int tid = threadIdx.x;
  const int lane = tid & 63;
  const int w = tid >> 6;
  const int r = lane & 15, g = lane >> 4;
  const int p = blockIdx.x, h = blockIdx.y, b = blockIdx.z;
  const int hkv = h >> 2;

  const u16* Kp = Kg + (((size_t)b * 8 + hkv) * 2048) * 128;
  const u16* Vp = Vg + (((size_t)b * 8 + hkv) * 2048) * 128;

  // V staging assignment: thread stages d rows {vd0, vd0+1}, kv window [w*16, w*16+16)
  const int vd0 = lane * 2;
  const int vph_base = (vd0 >> 1) & 7;  // = lane & 7

#pragma unroll 1
  for (int phase = 0; phase < 2; ++phase) {
    const int qt = phase == 0 ? (31 - p) : p;
    const u16* Qp = Q + (((size_t)b * 32 + h) * 2048 + qt * 64 + w * 16) * 128;

    // Q fragments: A-operand row = r, k(d) = kk*32 + g*8 + e
    bf16x8 qf[4];
#pragma unroll
    for (int kk = 0; kk < 4; ++kk)
      qf[kk] = *(const bf16x8*)(Qp + r * 128 + kk * 32 + g * 8);

    f32x4 off[8];
#pragma unroll
    for (int i = 0; i < 8; ++i) off[i] = (f32x4){0.f, 0.f, 0.f, 0.f};
    float mrun[4], lrun[4];
#pragma unroll
    for (int j = 0; j < 4; ++j) { mrun[j] = -1e30f; lrun[j] = 0.f; }

    const int q_base = qt * 64 + w * 16 + g * 4;
    const int nu = qt + 1;  // 64-wide KV units

    for (int kt = 0; kt < nu; ++kt) {
      // ---- stage K via global_load_lds (swizzled granules)
#pragma unroll
      for (int c = 0; c < 4; ++c) {
        int t = c * 256 + tid;  // 16B slot in [0,1024)
        int krow = t >> 4;
        int kcc = (t & 15) ^ (krow & 7);
        gload16(Kp + (size_t)(kt * 64 + krow) * 128 + kcc * 8,
                (char*)Ks + c * 4096 + w * 1024);
      }
      // ---- stage V transposed via registers (coalesced u32 global loads)
      {
        unsigned vv[16];
#pragma unroll
        for (int i = 0; i < 16; ++i)
          vv[i] = *(const unsigned*)(Vp + (size_t)(kt * 64 + w * 16 + i) * 128 + vd0);
        u32x4 q0, q1, q2, q3;
#pragma unroll
        for (int i = 0; i < 4; ++i) {
          q0[i] = (vv[2 * i] & 0xffffu) | (vv[2 * i + 1] << 16);        // d0, kv w*16+0..7
          q1[i] = (vv[8 + 2 * i] & 0xffffu) | (vv[8 + 2 * i + 1] << 16); // d0, kv +8..15
          q2[i] = (vv[2 * i] >> 16) | (vv[2 * i + 1] & 0xffff0000u);    // d0+1, kv 0..7
          q3[i] = (vv[8 + 2 * i] >> 16) | (vv[8 + 2 * i + 1] & 0xffff0000u);
        }
        int g0 = w * 2, g1 = w * 2 + 1;
        *(u32x4*)((char*)Vt + (size_t)vd0 * 128 + (g0 ^ vph_base) * 16) = q0;
        *(u32x4*)((char*)Vt + (size_t)vd0 * 128 + (g1 ^ vph_base) * 16) = q1;
        *(u32x4*)((char*)Vt + (size_t)(vd0 + 1) * 128 + (g0 ^ vph_base) * 16) = q2;
        *(u32x4*)((char*)Vt + (size_t)(vd0 + 1) * 128 + (g1 ^ vph_base) * 16) = q3;
      }
      __syncthreads();

      // ---- S = Q K^T  (D[q][kv]: col=r is kv, row=g*4+j is q)
      f32x4 sc[4];
#pragma unroll
      for (int ni = 0; ni < 4; ++ni) {
        f32x4 a = (f32x4){0.f, 0.f, 0.f, 0.f};
        int ro = ni * 16 + r;
#pragma unroll
        for (int kk = 0; kk < 4; ++kk) {
          int slot = (ro * 16 + kk * 4 + g) ^ (ro & 7);
          bf16x8 kf = *(const bf16x8*)((const char*)Ks + slot * 16);
          a = __builtin_amdgcn_mfma_f32_16x16x32_bf16(qf[kk], kf, a, 0, 0, 0);
        }
        sc[ni] = a;
      }

      // ---- mask (diagonal unit only) + tile max
      float pm[4] = {-3e30f, -3e30f, -3e30f, -3e30f};
      if (kt == qt) {
#pragma unroll
        for (int ni = 0; ni < 4; ++ni) {
          int kvg = kt * 64 + ni * 16 + r;
#pragma unroll
          for (int j = 0; j < 4; ++j) {
            float sv = sc[ni][j];
            sv = (kvg > q_base + j) ? -1e30f : sv;
            sc[ni][j] = sv;
            pm[j] = fmaxf(pm[j], sv);
          }
        }
      } else {
#pragma unroll
        for (int ni = 0; ni < 4; ++ni)
#pragma unroll
          for (int j = 0; j < 4; ++j) pm[j] = fmaxf(pm[j], sc[ni][j]);
      }
#pragma unroll
      for (int j = 0; j < 4; ++j) {
        pm[j] = fmaxf(pm[j], __shfl_xor(pm[j], 1));
        pm[j] = fmaxf(pm[j], __shfl_xor(pm[j], 2));
        pm[j] = fmaxf(pm[j], __shfl_xor(pm[j], 4));
        pm[j] = fmaxf(pm[j], __shfl_xor(pm[j], 8));
      }

      // ---- defer-rescale (THR=8): only update m / rescale O when needed
      bool need = false;
#pragma unroll
      for (int j = 0; j < 4; ++j) need = need || (pm[j] > mrun[j] + 8.0f);
      if (__any(need)) {
        float sclv[4];
#pragma unroll
        for (int j = 0; j < 4; ++j) {
          float mn = fmaxf(mrun[j], pm[j]);
          sclv[j] = __expf(mrun[j] - mn);
          mrun[j] = mn;
          lrun[j] *= sclv[j];
        }
#pragma unroll
        for (int i = 0; i < 8; ++i)
#pragma unroll
          for (int j = 0; j < 4; ++j) off[i][j] *= sclv[j];
      }

      // ---- P = exp(S - m), partial sums, pack to bf16
      float psum[4] = {0.f, 0.f, 0.f, 0.f};
      u16 pb[4][4];
#pragma unroll
      for (int ni = 0; ni < 4; ++ni)
#pragma unroll
        for (int j = 0; j < 4; ++j) {
          float pv = __expf(sc[ni][j] - mrun[j]);
          psum[j] += pv;
          pb[ni][j] = f2b(pv);
        }
#pragma unroll
      for (int j = 0; j < 4; ++j) {
        psum[j] += __shfl_xor(psum[j], 1);
        psum[j] += __shfl_xor(psum[j], 2);
        psum[j] += __shfl_xor(psum[j], 4);
        psum[j] += __shfl_xor(psum[j], 8);
        lrun[j] += psum[j];
      }

      // ---- P -> per-wave LDS (swizzled), then A-operand frags
#pragma unroll
      for (int ni = 0; ni < 4; ++ni)
#pragma unroll
        for (int j = 0; j < 4; ++j) {
          int row = g * 4 + j;
          int kv = ni * 16 + r;
          int pg = (kv >> 3) ^ (row & 7);
          Plds[w][row * 64 + pg * 8 + (kv & 7)] = pb[ni][j];
        }
      bf16x8 pa[2];
#pragma unroll
      for (int kk = 0; kk < 2; ++kk) {
        int pg = (kk * 4 + g) ^ (r & 7);
        pa[kk] = *(const bf16x8*)(&Plds[w][0] + r * 64 + pg * 8);
      }

      // ---- O += P V : B-operand col(d)=dd*16+r, k(kv)=kk*32+g*8+e
#pragma unroll
      for (int dd = 0; dd < 8; ++dd) {
        int d = dd * 16 + r;
#pragma unroll
        for (int kk = 0; kk < 2; ++kk) {
          int ph = (kk * 4 + g) ^ ((r >> 1) & 7);
          bf16x8 vf = *(const bf16x8*)((const char*)Vt + (size_t)d * 128 + ph * 16);
          off[dd] = __builtin_amdgcn_mfma_f32_16x16x32_bf16(pa[kk], vf, off[dd], 0, 0, 0);
        }
      }
      __syncthreads();  // all waves done with Ks/Vt/Plds before restage
    }

    // ---- epilogue for this phase
    const size_t orow_base = (size_t)b * 2048 + qt * 64 + w * 16 + g * 4;
#pragma unroll
    for (int j = 0; j < 4; ++j) {
      float invl = 1.0f / lrun[j];
#pragma unroll
      for (int dd = 0; dd < 8; ++dd) {
        AO[(orow_base + j) * 4096 + h * 128 + dd * 16 + r] = f2b(off[dd][j] * invl);
      }
    }
  }
}

// ---------------- launch ----------------
extern "C" void kernel_launch(void* const* d_in, const int* in_sizes, int n_in,
                              void* d_out, int out_size, void* d_ws, size_t ws_size,
                              hipStream_t stream) {
  (void)in_sizes; (void)n_in; (void)out_size; (void)ws_size;
  const float* hs = (const float*)d_in[0];
  const float* cosT = (const float*)d_in[1];
  const float* sinT = (const float*)d_in[2];
  const float* wq = (const float*)d_in[3];
  const float* wk = (const float*)d_in[4];
  const float* wv = (const float*)d_in[5];
  const float* wo = (const float*)d_in[6];
  const float* qnw = (const float*)d_in[7];
  const float* knw = (const float*)d_in[8];
  float* out = (float*)d_out;

  char* ws = (char*)d_ws;
  u16* hsb  = (u16*)(ws);                   // [4096,2048]      16 MB
  u16* wqkv = (u16*)(ws + 16777216);        // [6144,2048]      24 MB
  u16* wob  = (u16*)(ws + 41943040);        // [2048,4096]      16 MB
  u16* Qb   = (u16*)(ws + 58720256);        // [2,32,2048,128]  32 MB
  u16* Kb   = (u16*)(ws + 92274688);        // [2,8,2048,128]    8 MB
  u16* Vb   = (u16*)(ws + 100663296);       // [2,8,2048,128]    8 MB
  u16* AO   = (u16*)(ws + 109051904);       // [4096,4096]      32 MB

  // 1) fp32 -> bf16
  cvt_bf16<<<4096, 256, 0, stream>>>(hs, hsb, 1048576);
  cvt_bf16<<<4096, 256, 0, stream>>>(wq, wqkv, 1048576);
  cvt_bf16<<<1024, 256, 0, stream>>>(wk, wqkv + (size_t)4096 * 2048, 262144);
  cvt_bf16<<<1024, 256, 0, stream>>>(wv, wqkv + (size_t)5120 * 2048, 262144);
  cvt_bf16<<<4096, 256, 0, stream>>>(wo, wob, 1048576);

  // 2) fused QKV projection, scatter into [B,H,S,D]
  gemm_bt<0><<<dim3(48, 32), 256, 0, stream>>>(hsb, wqkv, Qb, Kb, Vb, nullptr,
                                               4096, 6144, 2048);

  // 3) per-head RMSNorm + RoPE (Q gets softmax scale folded in)
  rms_rope<<<32768, 256, 0, stream>>>(Qb, cosT, sinT, qnw, 131072, 0.08838834764831845f);
  rms_rope<<<8192, 256, 0, stream>>>(Kb, cosT, sinT, knw, 32768, 1.0f);

  // 4) causal GQA flash attention (paired Q-tiles) -> AO [B*S, 4096] bf16
  attn_fwd<<<dim3(16, 32, 2), 256, 0, stream>>>(Qb, Kb, Vb, AO);

  // 5) output projection -> fp32 d_out
  gemm_bt<1><<<dim3(16, 32), 256, 0, stream>>>(AO, wob, nullptr, nullptr, nullptr,
                                               out, 4096, 2048, 4096);
}

// Round 4
// 460.633 us; speedup vs baseline: 1.5290x; 1.0871x over previous
//
#include <hip/hip_runtime.h>

typedef unsigned short u16;
typedef __attribute__((ext_vector_type(8))) short bf16x8;
typedef __attribute__((ext_vector_type(4))) float f32x4;
typedef __attribute__((ext_vector_type(4))) unsigned int u32x4;

#define GAS __attribute__((address_space(1)))
#define LAS __attribute__((address_space(3)))

__device__ __forceinline__ void gload16(const void* g, void* l) {
  __builtin_amdgcn_global_load_lds((GAS void*)g, (LAS void*)l, 16, 0, 0);
}
__device__ __forceinline__ u16 f2b(float x) {
  union { float f; unsigned u; } c; c.f = x;
  unsigned r = c.u + 0x7fffu + ((c.u >> 16) & 1u);
  return (u16)(r >> 16);
}
__device__ __forceinline__ float b2f(u16 h) {
  union { unsigned u; float f; } c; c.u = ((unsigned)h) << 16;
  return c.f;
}

// ---------------- fp32 -> bf16 conversion (8 elems/thread) ----------------
__global__ __launch_bounds__(256) void cvt_bf16(const float* __restrict__ src,
                                                u16* __restrict__ dst, int n8) {
  int i = blockIdx.x * 256 + threadIdx.x;
  if (i >= n8) return;
  const float4* s4 = (const float4*)src;
  float4 a = s4[(size_t)i * 2], b = s4[(size_t)i * 2 + 1];
  u32x4 v;
  v[0] = (unsigned)f2b(a.x) | ((unsigned)f2b(a.y) << 16);
  v[1] = (unsigned)f2b(a.z) | ((unsigned)f2b(a.w) << 16);
  v[2] = (unsigned)f2b(b.x) | ((unsigned)f2b(b.y) << 16);
  v[3] = (unsigned)f2b(b.z) | ((unsigned)f2b(b.w) << 16);
  *(u32x4*)(dst + (size_t)i * 8) = v;
}

// ---------------- GEMM: C[m,n] = sum_k A[m,k]*B[n,k]  (B given row=n, K-major)
// 128x128 tile, BK=32, 4 waves (2x2), each wave 64x64 via 4x4 mfma frags.
// LDS 16B-slot involution swizzle: phys(row,kc) = row*4 + (kc ^ (row&3)).
template <int MODE>
__global__ __launch_bounds__(256) void gemm_bt(
    const u16* __restrict__ A, const u16* __restrict__ B,
    u16* __restrict__ Dq, u16* __restrict__ Dk, u16* __restrict__ Dv,
    float* __restrict__ Dout, int M, int N, int K) {
  __shared__ __attribute__((aligned(16))) u16 As[128 * 32];
  __shared__ __attribute__((aligned(16))) u16 Bs[128 * 32];
  const int tid = threadIdx.x;
  const int lane = tid & 63;
  const int w = tid >> 6;
  const int wr = w >> 1, wc = w & 1;
  const int r = lane & 15, g = lane >> 4;
  const int m0 = blockIdx.y * 128, n0 = blockIdx.x * 128;
  (void)M; (void)N;

  f32x4 acc[4][4];
#pragma unroll
  for (int i = 0; i < 4; ++i)
#pragma unroll
    for (int j = 0; j < 4; ++j) acc[i][j] = (f32x4){0.f, 0.f, 0.f, 0.f};

  for (int k0 = 0; k0 < K; k0 += 32) {
#pragma unroll
    for (int c = 0; c < 2; ++c) {
      int t = c * 256 + tid;          // 16B slot index in [0,512)
      int row = t >> 2;               // row unchanged by swizzle (XOR hits bits 0-1)
      int kc = (t & 3) ^ ((t >> 2) & 3);
      gload16(A + (size_t)(m0 + row) * K + k0 + kc * 8, (char*)As + c * 4096 + w * 1024);
      gload16(B + (size_t)(n0 + row) * K + k0 + kc * 8, (char*)Bs + c * 4096 + w * 1024);
    }
    __syncthreads();  // drains vmcnt; LDS tiles ready

    bf16x8 af[4], bfr[4];
#pragma unroll
    for (int mi = 0; mi < 4; ++mi) {
      int ro = wr * 64 + mi * 16 + r;
      int slot = (ro * 4 + g) ^ (ro & 3);
      af[mi] = *(const bf16x8*)((const char*)As + slot * 16);
    }
#pragma unroll
    for (int ni = 0; ni < 4; ++ni) {
      int ro = wc * 64 + ni * 16 + r;
      int slot = (ro * 4 + g) ^ (ro & 3);
      bfr[ni] = *(const bf16x8*)((const char*)Bs + slot * 16);
    }
#pragma unroll
    for (int mi = 0; mi < 4; ++mi)
#pragma unroll
      for (int ni = 0; ni < 4; ++ni)
        acc[mi][ni] = __builtin_amdgcn_mfma_f32_16x16x32_bf16(af[mi], bfr[ni],
                                                              acc[mi][ni], 0, 0, 0);
    __syncthreads();  // all reads done before restage
  }

  // Epilogue. D layout: col = lane&15 (=r), row = (lane>>4)*4 + j (=g*4+j).
#pragma unroll
  for (int mi = 0; mi < 4; ++mi)
#pragma unroll
    for (int ni = 0; ni < 4; ++ni)
#pragma unroll
      for (int j = 0; j < 4; ++j) {
        int m = m0 + wr * 64 + mi * 16 + g * 4 + j;
        int n = n0 + wc * 64 + ni * 16 + r;
        float v = acc[mi][ni][j];
        if (MODE == 0) {
          u16 hv = f2b(v);
          int b = m >> 11, s = m & 2047;
          if (n < 4096) {
            Dq[(((size_t)b * 32 + (n >> 7)) * 2048 + s) * 128 + (n & 127)] = hv;
          } else if (n < 5120) {
            int nn = n - 4096;
            Dk[(((size_t)b * 8 + (nn >> 7)) * 2048 + s) * 128 + (nn & 127)] = hv;
          } else {
            int nn = n - 5120;
            Dv[(((size_t)b * 8 + (nn >> 7)) * 2048 + s) * 128 + (nn & 127)] = hv;
          }
        } else {
          Dout[(size_t)m * 2048 + n] = v;
        }
      }
}

// ---------------- fused per-head RMSNorm + RoPE (in place, bf16) ----------------
__global__ __launch_bounds__(256) void rms_rope(u16* __restrict__ X,
                                                const float* __restrict__ cosT,
                                                const float* __restrict__ sinT,
                                                const float* __restrict__ nw,
                                                int nrows, float oscale) {
  int idx = blockIdx.x * 256 + threadIdx.x;
  int row = idx >> 6;
  int lane = idx & 63;
  if (row >= nrows) return;
  int s = row & 2047;  // S = 2048
  u16* rp = X + (size_t)row * 128;
  float x0 = b2f(rp[lane]);
  float x1 = b2f(rp[lane + 64]);
  float ss = x0 * x0 + x1 * x1;
#pragma unroll
  for (int m = 32; m >= 1; m >>= 1) ss += __shfl_xor(ss, m);
  float inv = rsqrtf(ss * (1.0f / 128.0f) + 1e-6f);
  x0 *= inv * nw[lane];
  x1 *= inv * nw[lane + 64];
  float c0 = cosT[s * 128 + lane], s0 = sinT[s * 128 + lane];
  float c1 = cosT[s * 128 + lane + 64], s1 = sinT[s * 128 + lane + 64];
  rp[lane] = f2b((x0 * c0 - x1 * s0) * oscale);
  rp[lane + 64] = f2b((x1 * c1 + x0 * s1) * oscale);
}

// ---------------- causal GQA flash attention (paired Q-tiles) ----------------
// block p handles Q-tiles {31-p, p} (uniform 33 KV-units). 4 waves x 16 q-rows.
// KVBLK = 64. SWAPPED QK^T: S^T = mfma(K_frag, Q_frag) so each lane owns one
// full q-row (q = w*16 + r) -> softmax is in-lane + 2 shfl_xor. exp2 domain
// (log2e folded into Q scale). P packed to u32 pairs -> 8 ds_write_b32 into
// swizzled per-wave Plds -> 2 ds_read_b128 A-fragments.
__global__ __launch_bounds__(256) void attn_fwd(const u16* __restrict__ Q,
                                                const u16* __restrict__ Kg,
                                                const u16* __restrict__ Vg,
                                                u16* __restrict__ AO) {
  __shared__ __attribute__((aligned(16))) u16 Ks[64 * 128];
  __shared__ __attribute__((aligned(16))) u16 Vt[128 * 64];
  __shared__ __attribute__((aligned(16))) u16 Plds[4][16 * 64];
  const int tid = threadIdx.x;
  const int lane = tid & 63;
  const int w = tid >> 6;
  const int r = lane & 15, g = lane >> 4;
  const int p = blockIdx.x, h = blockIdx.y, b = blockIdx.z;
  const int hkv = h >> 2;

  const u16* Kp = Kg + (((size_t)b * 8 + hkv) * 2048) * 128;
  const u16* Vp = Vg + (((size_t)b * 8 + hkv) * 2048) * 128;

  // V staging assignment: thread stages d rows {vd0, vd0+1}, kv window [w*16, w*16+16)
  const int vd0 = lane * 2;
  const int vph_base = (vd0 >> 1) & 7;  // = lane & 7

#pragma unroll 1
  for (int phase = 0; phase < 2; ++phase) {
    const int qt = phase == 0 ? (31 - p) : p;
    const u16* Qp = Q + (((size_t)b * 32 + h) * 2048 + qt * 64 + w * 16) * 128;

    // Q fragments (B-operand): row q = r, k(d) = kk*32 + g*8 + e
    bf16x8 qf[4];
#pragma unroll
    for (int kk = 0; kk < 4; ++kk)
      qf[kk] = *(const bf16x8*)(Qp + r * 128 + kk * 32 + g * 8);

    f32x4 off[8];
#pragma unroll
    for (int i = 0; i < 8; ++i) off[i] = (f32x4){0.f, 0.f, 0.f, 0.f};
    float mrun = -1e30f, lrun = 0.f;  // per-lane: q-row = w*16 + r

    const int qg = qt * 64 + w * 16 + r;  // this lane's global q row
    const int nu = qt + 1;                // 64-wide KV units

    for (int kt = 0; kt < nu; ++kt) {
      // ---- stage K via global_load_lds (swizzled granules)
#pragma unroll
      for (int c = 0; c < 4; ++c) {
        int t = c * 256 + tid;  // 16B slot in [0,1024)
        int krow = t >> 4;
        int kcc = (t & 15) ^ (krow & 7);
        gload16(Kp + (size_t)(kt * 64 + krow) * 128 + kcc * 8,
                (char*)Ks + c * 4096 + w * 1024);
      }
      // ---- stage V transposed via registers (coalesced u32 global loads)
      {
        unsigned vv[16];
#pragma unroll
        for (int i = 0; i < 16; ++i)
          vv[i] = *(const unsigned*)(Vp + (size_t)(kt * 64 + w * 16 + i) * 128 + vd0);
        u32x4 q0, q1, q2, q3;
#pragma unroll
        for (int i = 0; i < 4; ++i) {
          q0[i] = (vv[2 * i] & 0xffffu) | (vv[2 * i + 1] << 16);
          q1[i] = (vv[8 + 2 * i] & 0xffffu) | (vv[8 + 2 * i + 1] << 16);
          q2[i] = (vv[2 * i] >> 16) | (vv[2 * i + 1] & 0xffff0000u);
          q3[i] = (vv[8 + 2 * i] >> 16) | (vv[8 + 2 * i + 1] & 0xffff0000u);
        }
        int g0 = w * 2, g1 = w * 2 + 1;
        *(u32x4*)((char*)Vt + (size_t)vd0 * 128 + (g0 ^ vph_base) * 16) = q0;
        *(u32x4*)((char*)Vt + (size_t)vd0 * 128 + (g1 ^ vph_base) * 16) = q1;
        *(u32x4*)((char*)Vt + (size_t)(vd0 + 1) * 128 + (g0 ^ vph_base) * 16) = q2;
        *(u32x4*)((char*)Vt + (size_t)(vd0 + 1) * 128 + (g1 ^ vph_base) * 16) = q3;
      }
      __syncthreads();

      // ---- S^T = K Q^T (swapped): D col = q = r, D row = kv = ni*16 + g*4 + j
      f32x4 sc[4];
#pragma unroll
      for (int ni = 0; ni < 4; ++ni) {
        f32x4 a = (f32x4){0.f, 0.f, 0.f, 0.f};
        int ro = ni * 16 + r;
#pragma unroll
        for (int kk = 0; kk < 4; ++kk) {
          int slot = (ro * 16 + kk * 4 + g) ^ (ro & 7);
          bf16x8 kf = *(const bf16x8*)((const char*)Ks + slot * 16);
          a = __builtin_amdgcn_mfma_f32_16x16x32_bf16(kf, qf[kk], a, 0, 0, 0);
        }
        sc[ni] = a;
      }

      // ---- mask (diagonal unit only) + in-lane max
      float pm = -3e30f;
      if (kt == qt) {
#pragma unroll
        for (int ni = 0; ni < 4; ++ni)
#pragma unroll
          for (int j = 0; j < 4; ++j) {
            int kvg = kt * 64 + ni * 16 + g * 4 + j;
            float sv = sc[ni][j];
            sv = (kvg > qg) ? -1e30f : sv;
            sc[ni][j] = sv;
            pm = fmaxf(pm, sv);
          }
      } else {
#pragma unroll
        for (int ni = 0; ni < 4; ++ni)
#pragma unroll
          for (int j = 0; j < 4; ++j) pm = fmaxf(pm, sc[ni][j]);
      }
      pm = fmaxf(pm, __shfl_xor(pm, 16));
      pm = fmaxf(pm, __shfl_xor(pm, 32));

      // ---- defer-rescale (log2 units, THR=11 ~ e^7.6)
      if (__any(pm > mrun + 11.0f)) {
        float mn = fmaxf(mrun, pm);
        float sclq = exp2f(mrun - mn);
        mrun = mn;
        lrun *= sclq;
        // redistribute scl to PV-output rows (q16 = g*4+j lives at lane r = g*4+j)
        float s0 = __shfl(sclq, g * 4 + 0);
        float s1 = __shfl(sclq, g * 4 + 1);
        float s2 = __shfl(sclq, g * 4 + 2);
        float s3 = __shfl(sclq, g * 4 + 3);
#pragma unroll
        for (int i = 0; i < 8; ++i) {
          off[i][0] *= s0; off[i][1] *= s1; off[i][2] *= s2; off[i][3] *= s3;
        }
      }

      // ---- P = exp2(S - m), in-lane partial sum, pack u32 pairs
      float psum = 0.f;
      unsigned pk[4][2];
#pragma unroll
      for (int ni = 0; ni < 4; ++ni) {
        float p0 = exp2f(sc[ni][0] - mrun);
        float p1 = exp2f(sc[ni][1] - mrun);
        float p2 = exp2f(sc[ni][2] - mrun);
        float p3 = exp2f(sc[ni][3] - mrun);
        psum += (p0 + p1) + (p2 + p3);
        pk[ni][0] = (unsigned)f2b(p0) | ((unsigned)f2b(p1) << 16);
        pk[ni][1] = (unsigned)f2b(p2) | ((unsigned)f2b(p3) << 16);
      }
      psum += __shfl_xor(psum, 16);
      psum += __shfl_xor(psum, 32);
      lrun += psum;

      // ---- P row (q=r) -> per-wave swizzled LDS (8x ds_write_b32)
      {
        char* pw = (char*)&Plds[w][0];
        int base = r * 128;
        int sw = (r & 7) << 4;
#pragma unroll
        for (int ni = 0; ni < 4; ++ni) {
#pragma unroll
          for (int hh = 0; hh < 2; ++hh)
            *(unsigned*)(pw + ((base + ni * 32 + g * 8 + hh * 4) ^ sw)) = pk[ni][hh];
        }
      }
      bf16x8 pa[2];
      {
        const char* pw = (const char*)&Plds[w][0];
        int sw = (r & 7) << 4;
#pragma unroll
        for (int kk = 0; kk < 2; ++kk)
          pa[kk] = *(const bf16x8*)(pw + ((r * 128 + kk * 64 + g * 16) ^ sw));
      }

      // ---- O += P V : B-operand col(d)=dd*16+r, k(kv)=kk*32+g*8+e
#pragma unroll
      for (int dd = 0; dd < 8; ++dd) {
        int d = dd * 16 + r;
#pragma unroll
        for (int kk = 0; kk < 2; ++kk) {
          int ph = (kk * 4 + g) ^ ((r >> 1) & 7);
          bf16x8 vf = *(const bf16x8*)((const char*)Vt + (size_t)d * 128 + ph * 16);
          off[dd] = __builtin_amdgcn_mfma_f32_16x16x32_bf16(pa[kk], vf, off[dd], 0, 0, 0);
        }
      }
      __syncthreads();  // all waves done with Ks/Vt before restage
    }

    // ---- epilogue: O rows q16 = g*4+j; 1/lrun lives at lane r = q16
    float il = 1.0f / lrun;
    float il0 = __shfl(il, g * 4 + 0);
    float il1 = __shfl(il, g * 4 + 1);
    float il2 = __shfl(il, g * 4 + 2);
    float il3 = __shfl(il, g * 4 + 3);
    const size_t orow_base = (size_t)b * 2048 + qt * 64 + w * 16 + g * 4;
#pragma unroll
    for (int dd = 0; dd < 8; ++dd) {
      AO[(orow_base + 0) * 4096 + h * 128 + dd * 16 + r] = f2b(off[dd][0] * il0);
      AO[(orow_base + 1) * 4096 + h * 128 + dd * 16 + r] = f2b(off[dd][1] * il1);
      AO[(orow_base + 2) * 4096 + h * 128 + dd * 16 + r] = f2b(off[dd][2] * il2);
      AO[(orow_base + 3) * 4096 + h * 128 + dd * 16 + r] = f2b(off[dd][3] * il3);
    }
  }
}

// ---------------- launch ----------------
extern "C" void kernel_launch(void* const* d_in, const int* in_sizes, int n_in,
                              void* d_out, int out_size, void* d_ws, size_t ws_size,
                              hipStream_t stream) {
  (void)in_sizes; (void)n_in; (void)out_size; (void)ws_size;
  const float* hs = (const float*)d_in[0];
  const float* cosT = (const float*)d_in[1];
  const float* sinT = (const float*)d_in[2];
  const float* wq = (const float*)d_in[3];
  const float* wk = (const float*)d_in[4];
  const float* wv = (const float*)d_in[5];
  const float* wo = (const float*)d_in[6];
  const float* qnw = (const float*)d_in[7];
  const float* knw = (const float*)d_in[8];
  float* out = (float*)d_out;

  char* ws = (char*)d_ws;
  u16* hsb  = (u16*)(ws);                   // [4096,2048]      16 MB
  u16* wqkv = (u16*)(ws + 16777216);        // [6144,2048]      24 MB
  u16* wob  = (u16*)(ws + 41943040);        // [2048,4096]      16 MB
  u16* Qb   = (u16*)(ws + 58720256);        // [2,32,2048,128]  32 MB
  u16* Kb   = (u16*)(ws + 92274688);        // [2,8,2048,128]    8 MB
  u16* Vb   = (u16*)(ws + 100663296);       // [2,8,2048,128]    8 MB
  u16* AO   = (u16*)(ws + 109051904);       // [4096,4096]      32 MB

  // 1) fp32 -> bf16
  cvt_bf16<<<4096, 256, 0, stream>>>(hs, hsb, 1048576);
  cvt_bf16<<<4096, 256, 0, stream>>>(wq, wqkv, 1048576);
  cvt_bf16<<<1024, 256, 0, stream>>>(wk, wqkv + (size_t)4096 * 2048, 262144);
  cvt_bf16<<<1024, 256, 0, stream>>>(wv, wqkv + (size_t)5120 * 2048, 262144);
  cvt_bf16<<<4096, 256, 0, stream>>>(wo, wob, 1048576);

  // 2) fused QKV projection, scatter into [B,H,S,D]
  gemm_bt<0><<<dim3(48, 32), 256, 0, stream>>>(hsb, wqkv, Qb, Kb, Vb, nullptr,
                                               4096, 6144, 2048);

  // 3) per-head RMSNorm + RoPE (Q gets softmax scale * log2e folded in)
  rms_rope<<<32768, 256, 0, stream>>>(Qb, cosT, sinT, qnw, 131072,
                                      0.08838834764831845f * 1.4426950408889634f);
  rms_rope<<<8192, 256, 0, stream>>>(Kb, cosT, sinT, knw, 32768, 1.0f);

  // 4) causal GQA flash attention (paired Q-tiles) -> AO [B*S, 4096] bf16
  attn_fwd<<<dim3(16, 32, 2), 256, 0, stream>>>(Qb, Kb, Vb, AO);

  // 5) output projection -> fp32 d_out
  gemm_bt<1><<<dim3(16, 32), 256, 0, stream>>>(AO, wob, nullptr, nullptr, nullptr,
                                               out, 4096, 2048, 4096);
}